// Round 7
// baseline (136.277 us; speedup 1.0000x reference)
//
#include <hip/hip_runtime.h>
#include <math.h>

typedef float fx4 __attribute__((ext_vector_type(4)));

#define TM    64            // rows per block
#define KC    32            // K chunk per stream per iter
#define DDIM  2048
#define KHALF 1024          // K per stream (2 streams)
#define NI    (KHALF / KC)  // 32 iters
#define ENUM  64

// 4 waves: wv = {stream s = wv>>1, col-side cs = wv&1 (0:gate cols 0-63, 1:noise 64-127)}
// Each wave: 8x8 lane grid, 8x8 micro-tile -> 64 rows x 64 cols, 1 B/FMA from LDS.
// Streams split K in half; partial accumulators combined in hbuf at epilogue.

__global__ __launch_bounds__(256, 1)
void noisy_topk_kernel(const float* __restrict__ x,
                       const float* __restrict__ eps,
                       const float* __restrict__ Wg,
                       const float* __restrict__ gb,
                       const float* __restrict__ Wn,
                       const float* __restrict__ nb,
                       float* __restrict__ out)
{
    __shared__ float xs[2][2][KC][TM];    // [stream][buf][k][row]  32 KB
    __shared__ float ws[2][2][KC][128];   // [stream][buf][k][col]  64 KB
    __shared__ float hbuf[TM][133];       // 34 KB (pad 5: spreads lr across banks)
    __shared__ float pv1[TM][4], pv2[TM][4];
    __shared__ int   pi1[TM][4], pi2[TM][4];
    __shared__ float tp1[TM], tp2[TM];
    __shared__ int   ti1[TM], ti2[TM];

    const int tid  = threadIdx.x;
    const int lane = tid & 63;
    const int wv   = tid >> 6;
    const int s    = wv >> 1;            // k-stream 0/1
    const int cs   = wv & 1;             // 0: gate cols, 1: noise cols
    const int lr   = lane >> 3;          // lane row-group 0..7
    const int lc   = lane & 7;           // lane col-group 0..7
    const int row0 = blockIdx.x * TM;

    const int xoff = lr * 8;             // rows lr*8 .. +7
    const int woff = cs * 64 + lc * 8;   // cols in [0,128)

    // ---- staging maps: 128 threads per stream ----
    const int sst  = tid >> 7;           // staged stream
    const int xrow = tid & 63;           // x: row
    const int xq   = (tid >> 6) & 1;     // x: which 16-k half of the chunk
    const float* xp = x + (size_t)(row0 + xrow) * DDIM + sst * KHALF + xq * 16;
    const int wcol = tid & 127;          // w: col (0..63 gate, 64..127 noise)
    const float* wp = ((wcol < ENUM) ? (Wg + (size_t)wcol * DDIM)
                                     : (Wn + (size_t)(wcol - ENUM) * DDIM))
                      + sst * KHALF;

    float acc[8][8];
    #pragma unroll
    for (int r = 0; r < 8; ++r)
        #pragma unroll
        for (int c = 0; c < 8; ++c) acc[r][c] = 0.f;

    fx4 xr[4], wr[8];

    // ---- prologue: stage iter 0 into buf 0, preload iter 1 into regs ----
    #pragma unroll
    for (int j = 0; j < 4; ++j) xr[j] = *(const fx4*)(xp + j * 4);
    #pragma unroll
    for (int j = 0; j < 8; ++j) wr[j] = *(const fx4*)(wp + j * 4);
    #pragma unroll
    for (int j = 0; j < 4; ++j)
        #pragma unroll
        for (int e = 0; e < 4; ++e)
            xs[sst][0][xq * 16 + j * 4 + e][xrow] = xr[j][e];
    #pragma unroll
    for (int j = 0; j < 8; ++j)
        #pragma unroll
        for (int e = 0; e < 4; ++e)
            ws[sst][0][j * 4 + e][wcol] = wr[j][e];
    #pragma unroll
    for (int j = 0; j < 4; ++j) xr[j] = *(const fx4*)(xp + KC + j * 4);
    #pragma unroll
    for (int j = 0; j < 8; ++j) wr[j] = *(const fx4*)(wp + KC + j * 4);
    __syncthreads();

    for (int i = 0; i < NI; ++i) {
        const int cur = i & 1;
        const int nxt = cur ^ 1;

        // stage iter i+1 (in regs) into the other buffer
        if (i + 1 < NI) {
            #pragma unroll
            for (int j = 0; j < 4; ++j)
                #pragma unroll
                for (int e = 0; e < 4; ++e)
                    xs[sst][nxt][xq * 16 + j * 4 + e][xrow] = xr[j][e];
            #pragma unroll
            for (int j = 0; j < 8; ++j)
                #pragma unroll
                for (int e = 0; e < 4; ++e)
                    ws[sst][nxt][j * 4 + e][wcol] = wr[j][e];
        }
        // preload iter i+2 (latency hidden under a full iter of compute)
        if (i + 2 < NI) {
            const int ko = (i + 2) * KC;
            #pragma unroll
            for (int j = 0; j < 4; ++j) xr[j] = *(const fx4*)(xp + ko + j * 4);
            #pragma unroll
            for (int j = 0; j < 8; ++j) wr[j] = *(const fx4*)(wp + ko + j * 4);
        }

        // ---- compute chunk: 8 groups of 4 k, A/B register ping-pong ----
        const float* xb_ = &xs[s][cur][0][0];   // [k][64]
        const float* wb_ = &ws[s][cur][0][0];   // [k][128]
        fx4 xA[4][2], wA[4][2], xB[4][2], wB[4][2];

        #pragma unroll
        for (int kk = 0; kk < 4; ++kk) {
            xA[kk][0] = *(const fx4*)(xb_ + kk * TM + xoff);
            xA[kk][1] = *(const fx4*)(xb_ + kk * TM + xoff + 4);
            wA[kk][0] = *(const fx4*)(wb_ + kk * 128 + woff);
            wA[kk][1] = *(const fx4*)(wb_ + kk * 128 + woff + 4);
        }

        #pragma unroll
        for (int g = 0; g < 8; g += 2) {
            #pragma unroll
            for (int kk = 0; kk < 4; ++kk) {
                const int kb = (g + 1) * 4 + kk;
                xB[kk][0] = *(const fx4*)(xb_ + kb * TM + xoff);
                xB[kk][1] = *(const fx4*)(xb_ + kb * TM + xoff + 4);
                wB[kk][0] = *(const fx4*)(wb_ + kb * 128 + woff);
                wB[kk][1] = *(const fx4*)(wb_ + kb * 128 + woff + 4);
            }
            #pragma unroll
            for (int kk = 0; kk < 4; ++kk)
                #pragma unroll
                for (int r = 0; r < 8; ++r) {
                    const float xv = xA[kk][r >> 2][r & 3];
                    #pragma unroll
                    for (int c = 0; c < 8; ++c)
                        acc[r][c] = fmaf(xv, wA[kk][c >> 2][c & 3], acc[r][c]);
                }
            if (g + 2 < 8) {
                #pragma unroll
                for (int kk = 0; kk < 4; ++kk) {
                    const int kb = (g + 2) * 4 + kk;
                    xA[kk][0] = *(const fx4*)(xb_ + kb * TM + xoff);
                    xA[kk][1] = *(const fx4*)(xb_ + kb * TM + xoff + 4);
                    wA[kk][0] = *(const fx4*)(wb_ + kb * 128 + woff);
                    wA[kk][1] = *(const fx4*)(wb_ + kb * 128 + woff + 4);
                }
            }
            #pragma unroll
            for (int kk = 0; kk < 4; ++kk)
                #pragma unroll
                for (int r = 0; r < 8; ++r) {
                    const float xv = xB[kk][r >> 2][r & 3];
                    #pragma unroll
                    for (int c = 0; c < 8; ++c)
                        acc[r][c] = fmaf(xv, wB[kk][c >> 2][c & 3], acc[r][c]);
                }
        }
        __syncthreads();
    }

    // ---- combine K-halves: stream 0 writes, stream 1 adds ----
    if (s == 0) {
        #pragma unroll
        for (int r = 0; r < 8; ++r) {
            fx4 o0, o1;
            #pragma unroll
            for (int c = 0; c < 4; ++c) { o0[c] = acc[r][c]; o1[c] = acc[r][c + 4]; }
            *(fx4*)&hbuf[lr * 8 + r][woff]     = o0;
            *(fx4*)&hbuf[lr * 8 + r][woff + 4] = o1;
        }
    }
    __syncthreads();
    if (s == 1) {
        #pragma unroll
        for (int r = 0; r < 8; ++r) {
            fx4 a0 = *(const fx4*)&hbuf[lr * 8 + r][woff];
            fx4 a1 = *(const fx4*)&hbuf[lr * 8 + r][woff + 4];
            #pragma unroll
            for (int c = 0; c < 4; ++c) { a0[c] += acc[r][c]; a1[c] += acc[r][c + 4]; }
            *(fx4*)&hbuf[lr * 8 + r][woff]     = a0;
            *(fx4*)&hbuf[lr * 8 + r][woff + 4] = a1;
        }
    }
    __syncthreads();

    // ---- epilogue: h = gate + eps*softplus(noise); partial top-2 (4 threads/row) ----
    const int rloc = tid >> 2;   // 0..63
    const int q    = tid & 3;    // expert range q*16 .. q*16+15
    {
        float v1 = -INFINITY, v2 = -INFINITY;
        int   i1 = -1, i2 = -1;
        const float* ep = eps + (size_t)(row0 + rloc) * ENUM + q * 16;
        #pragma unroll
        for (int v = 0; v < 4; ++v) {
            fx4 gv  = *(const fx4*)&hbuf[rloc][q * 16 + v * 4];
            fx4 nv  = *(const fx4*)&hbuf[rloc][ENUM + q * 16 + v * 4];
            fx4 ev  = *(const fx4*)(ep + v * 4);
            fx4 gbv = *(const fx4*)(gb + q * 16 + v * 4);
            fx4 nbv = *(const fx4*)(nb + q * 16 + v * 4);
            #pragma unroll
            for (int j = 0; j < 4; ++j) {
                float nz = nv[j] + nbv[j];
                float sp = fmaxf(nz, 0.f) + log1pf(expf(-fabsf(nz)));
                float h  = gv[j] + gbv[j] + ev[j] * sp;
                int   e  = q * 16 + v * 4 + j;
                if (h > v1)      { v2 = v1; i2 = i1; v1 = h; i1 = e; }
                else if (h > v2) { v2 = h;  i2 = e; }
            }
        }
        pv1[rloc][q] = v1; pv2[rloc][q] = v2;
        pi1[rloc][q] = i1; pi2[rloc][q] = i2;
    }
    __syncthreads();

    // ---- merge partials (1 thread/row), softmax over top-2 ----
    if (tid < TM) {
        float v1 = -INFINITY, v2 = -INFINITY;
        int   i1 = -1, i2 = -1;
        #pragma unroll
        for (int qq = 0; qq < 4; ++qq) {
            float a1 = pv1[tid][qq]; int b1 = pi1[tid][qq];
            float a2 = pv2[tid][qq]; int b2 = pi2[tid][qq];
            if (a1 > v1)      { v2 = v1; i2 = i1; v1 = a1; i1 = b1; }
            else if (a1 > v2) { v2 = a1; i2 = b1; }
            if (a2 > v1)      { v2 = v1; i2 = i1; v1 = a2; i1 = b2; }
            else if (a2 > v2) { v2 = a2; i2 = b2; }
        }
        float e2  = expf(v2 - v1);
        float inv = 1.f / (1.f + e2);
        tp1[tid] = inv;
        tp2[tid] = e2 * inv;
        ti1[tid] = i1; ti2[tid] = i2;
    }
    __syncthreads();

    // ---- coalesced output write ----
    {
        const int   orow = tid >> 2;
        const int   oq   = tid & 3;
        const int   a1 = ti1[orow], a2 = ti2[orow];
        const float p1 = tp1[orow], p2 = tp2[orow];
        float* op = out + (size_t)(row0 + orow) * ENUM + oq * 16;
        #pragma unroll
        for (int v = 0; v < 4; ++v) {
            fx4 o;
            #pragma unroll
            for (int j = 0; j < 4; ++j) {
                int e = oq * 16 + v * 4 + j;
                o[j] = (e == a1) ? p1 : ((e == a2) ? p2 : 0.f);
            }
            *(fx4*)(op + v * 4) = o;
        }
    }
}

extern "C" void kernel_launch(void* const* d_in, const int* in_sizes, int n_in,
                              void* d_out, int out_size, void* d_ws, size_t ws_size,
                              hipStream_t stream) {
    const float* x   = (const float*)d_in[0];
    const float* eps = (const float*)d_in[1];
    const float* Wg  = (const float*)d_in[2];
    const float* gbp = (const float*)d_in[3];
    const float* Wn  = (const float*)d_in[4];
    const float* nbp = (const float*)d_in[5];
    float* out = (float*)d_out;

    const int M = in_sizes[0] / DDIM;    // B*T = 16384
    dim3 grid(M / TM), block(256);
    hipLaunchKernelGGL(noisy_topk_kernel, grid, block, 0, stream,
                       x, eps, Wg, gbp, Wn, nbp, out);
}

// Round 8
// 106.438 us; speedup vs baseline: 1.2803x; 1.2803x over previous
//
#include <hip/hip_runtime.h>
#include <math.h>

typedef float fx4    __attribute__((ext_vector_type(4)));
typedef float f32x16 __attribute__((ext_vector_type(16)));
typedef short bf16x8 __attribute__((ext_vector_type(8)));

#define TM    64
#define KC    32
#define DDIM  2048
#define ENUM  64
#define NC    (DDIM / KC)    // 64 chunks
#define NKT   (DDIM / 16)    // 128 k-tiles of 16

__device__ __forceinline__ unsigned short bf16_rne(float f) {
    unsigned int u = __builtin_bit_cast(unsigned int, f);
    unsigned int r = u + 0x7FFFu + ((u >> 16) & 1u);
    return (unsigned short)(r >> 16);
}
__device__ __forceinline__ float bf16_f32(unsigned short h) {
    unsigned int u = ((unsigned int)h) << 16;
    return __builtin_bit_cast(float, u);
}

// ---------------- kernel 1: W -> bf16x3, frag-slot order ----------------
// ws layout (16-B slots): [split(3)][kt(128)][ct(4)][lane(64)]
// slot(s,kt,ct,l) holds W[ct*32+(l&31)][kt*16+(l>>5)*8 .. +8] for split s.
__global__ __launch_bounds__(256)
void convert_w(const float* __restrict__ Wg, const float* __restrict__ Wn,
               unsigned short* __restrict__ wsB) {
    const int t  = blockIdx.x * 256 + threadIdx.x;   // 0..32767
    const int l  = t & 63;
    const int ct = (t >> 6) & 3;
    const int kt = t >> 8;                            // 0..127
    const int col = ct * 32 + (l & 31);
    const int k0  = kt * 16 + (l >> 5) * 8;
    const float* src = ((col < ENUM) ? (Wg + (size_t)col * DDIM)
                                     : (Wn + (size_t)(col - ENUM) * DDIM)) + k0;
    bf16x8 vh, vm, vl;
    #pragma unroll
    for (int j = 0; j < 8; ++j) {
        float v = src[j];
        unsigned short h = bf16_rne(v);  float r1 = v  - bf16_f32(h);
        unsigned short m = bf16_rne(r1); float r2 = r1 - bf16_f32(m);
        unsigned short o = bf16_rne(r2);
        vh[j] = (short)h; vm[j] = (short)m; vl[j] = (short)o;
    }
    *(bf16x8*)(wsB + ((size_t)(0 * 32768 + t)) * 8) = vh;
    *(bf16x8*)(wsB + ((size_t)(1 * 32768 + t)) * 8) = vm;
    *(bf16x8*)(wsB + ((size_t)(2 * 32768 + t)) * 8) = vl;
}

// ---------------- kernel 2: MFMA GEMM + fused noisy-top2 ----------------
__global__ __launch_bounds__(256, 1)
void noisy_topk_mfma(const float* __restrict__ x,
                     const float* __restrict__ eps,
                     const float* __restrict__ gb,
                     const float* __restrict__ nb,
                     const unsigned short* __restrict__ wsB,
                     float* __restrict__ out)
{
    // A_lds 16-B slots: [buf(2)][split(3)][kstep(2)][rt(2)][slot(64)]
    __shared__ __align__(16) unsigned short A_lds[2 * 768 * 8];   // 24 KB
    __shared__ float hbuf[TM][132];                               // 33.8 KB
    __shared__ float pv1[TM][4], pv2[TM][4];
    __shared__ int   pi1[TM][4], pi2[TM][4];
    __shared__ float tp1[TM], tp2[TM];
    __shared__ int   ti1[TM], ti2[TM];

    const int tid  = threadIdx.x;
    const int lane = tid & 63;
    const int wv   = tid >> 6;           // wave = coltile ct (0..3)
    // XCD-aware bijective swizzle (grid 256 = 8*32)
    const int bs   = (blockIdx.x & 7) * 32 + (blockIdx.x >> 3);
    const int row0 = bs * TM;

    // ---- x staging map: lane -> row, wave -> k-subrange ----
    const float* xp = x + (size_t)(row0 + lane) * DDIM + wv * 8;

    // ---- A_lds write addressing (per thread, fixed) ----
    const int w_kstep = wv >> 1, w_khalf = wv & 1;
    const int w_rt = lane >> 5, w_r32 = lane & 31;
    const int slotRaw = w_khalf * 32 + w_r32;
    const int w_slot  = slotRaw ^ ((slotRaw >> 3) & 7);
    // read swizzle for compute
    const int r_slot  = lane ^ ((lane >> 3) & 7);

    f32x16 accA0 = {}, accA1 = {}, accB0 = {}, accB1 = {};

    fx4 xr0, xr1;  // staged fp32 x (8 floats) for next chunk

    // ---- prologue: chunk 0 -> LDS buf 0; chunk 1 -> regs ----
    {
        fx4 a0 = *(const fx4*)(xp);
        fx4 a1 = *(const fx4*)(xp + 4);
        bf16x8 vh, vm, vl;
        #pragma unroll
        for (int j = 0; j < 8; ++j) {
            float v = (j < 4) ? a0[j] : a1[j - 4];
            unsigned short h = bf16_rne(v);  float r1 = v  - bf16_f32(h);
            unsigned short m = bf16_rne(r1); float r2 = r1 - bf16_f32(m);
            unsigned short o = bf16_rne(r2);
            vh[j] = (short)h; vm[j] = (short)m; vl[j] = (short)o;
        }
        #pragma unroll
        for (int s = 0; s < 3; ++s) {
            const int off = (((s * 2 + w_kstep) * 2 + w_rt) * 64 + w_slot) * 8;
            *(bf16x8*)(&A_lds[off]) = (s == 0) ? vh : ((s == 1) ? vm : vl);
        }
        xr0 = *(const fx4*)(xp + KC);
        xr1 = *(const fx4*)(xp + KC + 4);
    }
    __syncthreads();

    for (int c = 0; c < NC; ++c) {
        const int cur = c & 1;
        const int nxt = cur ^ 1;
        const int ktb = c * 2;

        // ---- issue B loads for this chunk (6 x 1KB coalesced wave loads) ----
        #define BOFF(s, ks) ((((size_t)(s) * NKT + (ktb + (ks))) * 4 + wv) * 64 + lane) * 8
        const bf16x8 b0h = *(const bf16x8*)(wsB + BOFF(0, 0));
        const bf16x8 b0m = *(const bf16x8*)(wsB + BOFF(1, 0));
        const bf16x8 b0l = *(const bf16x8*)(wsB + BOFF(2, 0));
        const bf16x8 b1h = *(const bf16x8*)(wsB + BOFF(0, 1));
        const bf16x8 b1m = *(const bf16x8*)(wsB + BOFF(1, 1));
        const bf16x8 b1l = *(const bf16x8*)(wsB + BOFF(2, 1));
        #undef BOFF

        // ---- convert staged x (chunk c+1) -> A_lds[nxt] ----
        if (c + 1 < NC) {
            bf16x8 vh, vm, vl;
            #pragma unroll
            for (int j = 0; j < 8; ++j) {
                float v = (j < 4) ? xr0[j] : xr1[j - 4];
                unsigned short h = bf16_rne(v);  float r1 = v  - bf16_f32(h);
                unsigned short m = bf16_rne(r1); float r2 = r1 - bf16_f32(m);
                unsigned short o = bf16_rne(r2);
                vh[j] = (short)h; vm[j] = (short)m; vl[j] = (short)o;
            }
            const int base = nxt * 6144;
            #pragma unroll
            for (int s = 0; s < 3; ++s) {
                const int off = base + (((s * 2 + w_kstep) * 2 + w_rt) * 64 + w_slot) * 8;
                *(bf16x8*)(&A_lds[off]) = (s == 0) ? vh : ((s == 1) ? vm : vl);
            }
        }
        // ---- prefetch chunk c+2 fp32 x ----
        if (c + 2 < NC) {
            const int ko = (c + 2) * KC;
            xr0 = *(const fx4*)(xp + ko);
            xr1 = *(const fx4*)(xp + ko + 4);
        }

        // ---- A frag reads: 12 x b128 from buf cur ----
        const int abase = cur * 6144;
        #define ARD(s, ks, rt) (*(const bf16x8*)(&A_lds[abase + ((((s) * 2 + (ks)) * 2 + (rt)) * 64 + r_slot) * 8]))
        const bf16x8 a0h0 = ARD(0, 0, 0), a0h1 = ARD(0, 0, 1);
        const bf16x8 a0m0 = ARD(1, 0, 0), a0m1 = ARD(1, 0, 1);
        const bf16x8 a0l0 = ARD(2, 0, 0), a0l1 = ARD(2, 0, 1);
        const bf16x8 a1h0 = ARD(0, 1, 0), a1h1 = ARD(0, 1, 1);
        const bf16x8 a1m0 = ARD(1, 1, 0), a1m1 = ARD(1, 1, 1);
        const bf16x8 a1l0 = ARD(2, 1, 0), a1l1 = ARD(2, 1, 1);
        #undef ARD

        // ---- 24 MFMA (dual accumulators keep same-acc distance = 4) ----
        accA0 = __builtin_amdgcn_mfma_f32_32x32x16_bf16(a0h0, b0h, accA0, 0, 0, 0);
        accA1 = __builtin_amdgcn_mfma_f32_32x32x16_bf16(a0h1, b0h, accA1, 0, 0, 0);
        accB0 = __builtin_amdgcn_mfma_f32_32x32x16_bf16(a0h0, b0m, accB0, 0, 0, 0);
        accB1 = __builtin_amdgcn_mfma_f32_32x32x16_bf16(a0h1, b0m, accB1, 0, 0, 0);
        accA0 = __builtin_amdgcn_mfma_f32_32x32x16_bf16(a0m0, b0h, accA0, 0, 0, 0);
        accA1 = __builtin_amdgcn_mfma_f32_32x32x16_bf16(a0m1, b0h, accA1, 0, 0, 0);
        accB0 = __builtin_amdgcn_mfma_f32_32x32x16_bf16(a0m0, b0m, accB0, 0, 0, 0);
        accB1 = __builtin_amdgcn_mfma_f32_32x32x16_bf16(a0m1, b0m, accB1, 0, 0, 0);
        accA0 = __builtin_amdgcn_mfma_f32_32x32x16_bf16(a0h0, b0l, accA0, 0, 0, 0);
        accA1 = __builtin_amdgcn_mfma_f32_32x32x16_bf16(a0h1, b0l, accA1, 0, 0, 0);
        accB0 = __builtin_amdgcn_mfma_f32_32x32x16_bf16(a0l0, b0h, accB0, 0, 0, 0);
        accB1 = __builtin_amdgcn_mfma_f32_32x32x16_bf16(a0l1, b0h, accB1, 0, 0, 0);

        accA0 = __builtin_amdgcn_mfma_f32_32x32x16_bf16(a1h0, b1h, accA0, 0, 0, 0);
        accA1 = __builtin_amdgcn_mfma_f32_32x32x16_bf16(a1h1, b1h, accA1, 0, 0, 0);
        accB0 = __builtin_amdgcn_mfma_f32_32x32x16_bf16(a1h0, b1m, accB0, 0, 0, 0);
        accB1 = __builtin_amdgcn_mfma_f32_32x32x16_bf16(a1h1, b1m, accB1, 0, 0, 0);
        accA0 = __builtin_amdgcn_mfma_f32_32x32x16_bf16(a1m0, b1h, accA0, 0, 0, 0);
        accA1 = __builtin_amdgcn_mfma_f32_32x32x16_bf16(a1m1, b1h, accA1, 0, 0, 0);
        accB0 = __builtin_amdgcn_mfma_f32_32x32x16_bf16(a1m0, b1m, accB0, 0, 0, 0);
        accB1 = __builtin_amdgcn_mfma_f32_32x32x16_bf16(a1m1, b1m, accB1, 0, 0, 0);
        accA0 = __builtin_amdgcn_mfma_f32_32x32x16_bf16(a1h0, b1l, accA0, 0, 0, 0);
        accA1 = __builtin_amdgcn_mfma_f32_32x32x16_bf16(a1h1, b1l, accA1, 0, 0, 0);
        accB0 = __builtin_amdgcn_mfma_f32_32x32x16_bf16(a1l0, b1h, accB0, 0, 0, 0);
        accB1 = __builtin_amdgcn_mfma_f32_32x32x16_bf16(a1l1, b1h, accB1, 0, 0, 0);

        __syncthreads();
    }

    // ---- accumulators -> hbuf (C layout: col=lane&31, row=(r&3)+8*(r>>2)+4*(lane>>5)) ----
    {
        const f32x16 f0 = accA0 + accB0;
        const f32x16 f1 = accA1 + accB1;
        const int colb = wv * 32 + (lane & 31);
        const int rb   = 4 * (lane >> 5);
        #pragma unroll
        for (int r = 0; r < 16; ++r) {
            const int row = (r & 3) + 8 * (r >> 2) + rb;
            hbuf[row][colb]      = f0[r];
            hbuf[row + 32][colb] = f1[r];
        }
    }
    __syncthreads();

    // ---- epilogue: h = gate + eps*softplus(noise); partial top-2 (4 threads/row) ----
    const int rloc = tid >> 2;
    const int q    = tid & 3;
    {
        float v1 = -INFINITY, v2 = -INFINITY;
        int   i1 = -1, i2 = -1;
        const float* ep = eps + (size_t)(row0 + rloc) * ENUM + q * 16;
        #pragma unroll
        for (int v = 0; v < 4; ++v) {
            fx4 gv  = *(const fx4*)&hbuf[rloc][q * 16 + v * 4];
            fx4 nv  = *(const fx4*)&hbuf[rloc][ENUM + q * 16 + v * 4];
            fx4 ev  = *(const fx4*)(ep + v * 4);
            fx4 gbv = *(const fx4*)(gb + q * 16 + v * 4);
            fx4 nbv = *(const fx4*)(nb + q * 16 + v * 4);
            #pragma unroll
            for (int j = 0; j < 4; ++j) {
                float nz = nv[j] + nbv[j];
                float sp = fmaxf(nz, 0.f) + log1pf(expf(-fabsf(nz)));
                float h  = gv[j] + gbv[j] + ev[j] * sp;
                int   e  = q * 16 + v * 4 + j;
                if (h > v1)      { v2 = v1; i2 = i1; v1 = h; i1 = e; }
                else if (h > v2) { v2 = h;  i2 = e; }
            }
        }
        pv1[rloc][q] = v1; pv2[rloc][q] = v2;
        pi1[rloc][q] = i1; pi2[rloc][q] = i2;
    }
    __syncthreads();

    if (tid < TM) {
        float v1 = -INFINITY, v2 = -INFINITY;
        int   i1 = -1, i2 = -1;
        #pragma unroll
        for (int qq = 0; qq < 4; ++qq) {
            float a1 = pv1[tid][qq]; int b1 = pi1[tid][qq];
            float a2 = pv2[tid][qq]; int b2 = pi2[tid][qq];
            if (a1 > v1)      { v2 = v1; i2 = i1; v1 = a1; i1 = b1; }
            else if (a1 > v2) { v2 = a1; i2 = b1; }
            if (a2 > v1)      { v2 = v1; i2 = i1; v1 = a2; i1 = b2; }
            else if (a2 > v2) { v2 = a2; i2 = b2; }
        }
        float e2  = expf(v2 - v1);
        float inv = 1.f / (1.f + e2);
        tp1[tid] = inv;
        tp2[tid] = e2 * inv;
        ti1[tid] = i1; ti2[tid] = i2;
    }
    __syncthreads();

    {
        const int   orow = tid >> 2;
        const int   oq   = tid & 3;
        const int   a1 = ti1[orow], a2 = ti2[orow];
        const float p1 = tp1[orow], p2 = tp2[orow];
        float* op = out + (size_t)(row0 + orow) * ENUM + oq * 16;
        #pragma unroll
        for (int v = 0; v < 4; ++v) {
            fx4 o;
            #pragma unroll
            for (int j = 0; j < 4; ++j) {
                int e = oq * 16 + v * 4 + j;
                o[j] = (e == a1) ? p1 : ((e == a2) ? p2 : 0.f);
            }
            *(fx4*)(op + v * 4) = o;
        }
    }
}

extern "C" void kernel_launch(void* const* d_in, const int* in_sizes, int n_in,
                              void* d_out, int out_size, void* d_ws, size_t ws_size,
                              hipStream_t stream) {
    const float* x   = (const float*)d_in[0];
    const float* eps = (const float*)d_in[1];
    const float* Wg  = (const float*)d_in[2];
    const float* gbp = (const float*)d_in[3];
    const float* Wn  = (const float*)d_in[4];
    const float* nbp = (const float*)d_in[5];
    float* out = (float*)d_out;
    unsigned short* wsB = (unsigned short*)d_ws;   // needs 1.5 MB

    hipLaunchKernelGGL(convert_w, dim3(128), dim3(256), 0, stream, Wg, Wn, wsB);

    const int M = in_sizes[0] / DDIM;    // 16384
    hipLaunchKernelGGL(noisy_topk_mfma, dim3(M / TM), dim3(256), 0, stream,
                       x, eps, gbp, nbp, wsB, out);
}

// Round 9
// 82.725 us; speedup vs baseline: 1.6473x; 1.2866x over previous
//
#include <hip/hip_runtime.h>
#include <math.h>

typedef float fx4    __attribute__((ext_vector_type(4)));
typedef float f32x16 __attribute__((ext_vector_type(16)));
typedef short bf16x8 __attribute__((ext_vector_type(8)));
typedef short bf16x4 __attribute__((ext_vector_type(4)));

#define TM    64
#define KC    32
#define DDIM  2048
#define ENUM  64
#define NC    (DDIM / KC)    // 64 chunks
#define NKT   (DDIM / 16)    // 128 k-tiles of 16

__device__ __forceinline__ unsigned short bf16_rne(float f) {
    unsigned int u = __builtin_bit_cast(unsigned int, f);
    unsigned int r = u + 0x7FFFu + ((u >> 16) & 1u);
    return (unsigned short)(r >> 16);
}
__device__ __forceinline__ float bf16_f32(unsigned short h) {
    unsigned int u = ((unsigned int)h) << 16;
    return __builtin_bit_cast(float, u);
}

// ---------------- kernel 1: W -> bf16x3, frag-slot order (unchanged, R8-proven) ----------------
// wsB 16-B slots: [split(3)][kt(128)][ct(4)][lane(64)]
__global__ __launch_bounds__(256)
void convert_w(const float* __restrict__ Wg, const float* __restrict__ Wn,
               unsigned short* __restrict__ wsB) {
    const int t  = blockIdx.x * 256 + threadIdx.x;   // 0..32767
    const int l  = t & 63;
    const int ct = (t >> 6) & 3;
    const int kt = t >> 8;                            // 0..127
    const int col = ct * 32 + (l & 31);
    const int k0  = kt * 16 + (l >> 5) * 8;
    const float* src = ((col < ENUM) ? (Wg + (size_t)col * DDIM)
                                     : (Wn + (size_t)(col - ENUM) * DDIM)) + k0;
    bf16x8 vh, vm, vl;
    #pragma unroll
    for (int j = 0; j < 8; ++j) {
        float v = src[j];
        unsigned short h = bf16_rne(v);  float r1 = v  - bf16_f32(h);
        unsigned short m = bf16_rne(r1); float r2 = r1 - bf16_f32(m);
        unsigned short o = bf16_rne(r2);
        vh[j] = (short)h; vm[j] = (short)m; vl[j] = (short)o;
    }
    *(bf16x8*)(wsB + ((size_t)(0 * 32768 + t)) * 8) = vh;
    *(bf16x8*)(wsB + ((size_t)(1 * 32768 + t)) * 8) = vm;
    *(bf16x8*)(wsB + ((size_t)(2 * 32768 + t)) * 8) = vl;
}

// ---------------- kernel 2: 8-wave MFMA GEMM + fused noisy-top2 ----------------
__global__ __launch_bounds__(512, 2)
void noisy_topk_mfma(const float* __restrict__ x,
                     const float* __restrict__ eps,
                     const float* __restrict__ gb,
                     const float* __restrict__ nb,
                     const unsigned short* __restrict__ wsB,
                     float* __restrict__ out)
{
    // A_lds ushort idx: buf*6144 + s*2048 + kt*1024 + rt*512 + slot*8 (+ lo4*4)
    __shared__ __align__(16) unsigned short A_lds[2 * 6144];      // 24 KB
    __shared__ float hbuf[TM][132];                               // 33.8 KB
    __shared__ float pv1[TM][8], pv2[TM][8];
    __shared__ int   pi1[TM][8], pi2[TM][8];
    __shared__ float tp1[TM], tp2[TM];
    __shared__ int   ti1[TM], ti2[TM];

    const int tid  = threadIdx.x;
    const int lane = tid & 63;
    const int wv   = tid >> 6;           // 0..7
    const int ct   = wv & 3;             // col-tile (32 cols)
    const int rt   = wv >> 2;            // row-tile (32 rows)
    // XCD-aware bijective swizzle (grid 256 = 8*32)
    const int bs   = (blockIdx.x & 7) * 32 + (blockIdx.x >> 3);
    const int row0 = bs * TM;

    // ---- staging map: 512 threads, row-contiguous (coalesced 128B/row bursts) ----
    const int srow = tid >> 3;           // 0..63
    const int seg  = tid & 7;            // k sub-seg: 4 floats at seg*4
    const int kt_s = seg >> 2;
    const int hi8  = (seg >> 1) & 1;
    const int lo4  = seg & 1;
    const int rt_s = srow >> 5;
    const int slotRaw = hi8 * 32 + (srow & 31);
    const int wslot   = slotRaw ^ ((slotRaw >> 3) & 7);
    const int wbase   = kt_s * 1024 + rt_s * 512 + wslot * 8 + lo4 * 4;
    const float* xp = x + (size_t)(row0 + srow) * DDIM + seg * 4;

    // read swizzle for compute frags
    const int r_slot = lane ^ ((lane >> 3) & 7);
    const int rbase  = rt * 512 + r_slot * 8;

    f32x16 acc0 = {}, acc1 = {};
    fx4 xr;   // staged fp32 x (4 floats) for next chunk

    // ---- prologue: chunk 0 -> LDS buf 0; chunk 1 -> regs ----
    {
        fx4 v4 = *(const fx4*)(xp);
        bf16x4 vh, vm, vl;
        #pragma unroll
        for (int j = 0; j < 4; ++j) {
            float v = v4[j];
            unsigned short h = bf16_rne(v);  float r1 = v  - bf16_f32(h);
            unsigned short m = bf16_rne(r1); float r2 = r1 - bf16_f32(m);
            unsigned short o = bf16_rne(r2);
            vh[j] = (short)h; vm[j] = (short)m; vl[j] = (short)o;
        }
        *(bf16x4*)(&A_lds[0 * 2048 + wbase]) = vh;
        *(bf16x4*)(&A_lds[1 * 2048 + wbase]) = vm;
        *(bf16x4*)(&A_lds[2 * 2048 + wbase]) = vl;
        xr = *(const fx4*)(xp + KC);
    }
    __syncthreads();

    for (int c = 0; c < NC; ++c) {
        const int cur = c & 1;
        const int nxt = cur ^ 1;
        const int ktb = c * 2;

        // ---- B loads for this chunk (6 x 1KB coalesced wave loads, L2-resident) ----
        #define BOFF(s, ks) (((((size_t)(s) * NKT + (ktb + (ks))) * 4 + ct) * 64 + lane) * 8)
        const bf16x8 b0h = *(const bf16x8*)(wsB + BOFF(0, 0));
        const bf16x8 b0m = *(const bf16x8*)(wsB + BOFF(1, 0));
        const bf16x8 b0l = *(const bf16x8*)(wsB + BOFF(2, 0));
        const bf16x8 b1h = *(const bf16x8*)(wsB + BOFF(0, 1));
        const bf16x8 b1m = *(const bf16x8*)(wsB + BOFF(1, 1));
        const bf16x8 b1l = *(const bf16x8*)(wsB + BOFF(2, 1));
        #undef BOFF

        // ---- convert staged x (chunk c+1) -> A_lds[nxt] ----
        if (c + 1 < NC) {
            bf16x4 vh, vm, vl;
            #pragma unroll
            for (int j = 0; j < 4; ++j) {
                float v = xr[j];
                unsigned short h = bf16_rne(v);  float r1 = v  - bf16_f32(h);
                unsigned short m = bf16_rne(r1); float r2 = r1 - bf16_f32(m);
                unsigned short o = bf16_rne(r2);
                vh[j] = (short)h; vm[j] = (short)m; vl[j] = (short)o;
            }
            const int base = nxt * 6144;
            *(bf16x4*)(&A_lds[base + 0 * 2048 + wbase]) = vh;
            *(bf16x4*)(&A_lds[base + 1 * 2048 + wbase]) = vm;
            *(bf16x4*)(&A_lds[base + 2 * 2048 + wbase]) = vl;
        }
        // ---- prefetch chunk c+2 fp32 x (2-chunk distance covers HBM latency) ----
        if (c + 2 < NC) {
            xr = *(const fx4*)(xp + (c + 2) * KC);
        }

        // ---- A frag reads: 6 x b128 from buf cur (own row-tile only) ----
        const int abase = cur * 6144 + rbase;
        const bf16x8 a0h = *(const bf16x8*)(&A_lds[abase + 0 * 2048 + 0 * 1024]);
        const bf16x8 a0m = *(const bf16x8*)(&A_lds[abase + 1 * 2048 + 0 * 1024]);
        const bf16x8 a0l = *(const bf16x8*)(&A_lds[abase + 2 * 2048 + 0 * 1024]);
        const bf16x8 a1h = *(const bf16x8*)(&A_lds[abase + 0 * 2048 + 1 * 1024]);
        const bf16x8 a1m = *(const bf16x8*)(&A_lds[abase + 1 * 2048 + 1 * 1024]);
        const bf16x8 a1l = *(const bf16x8*)(&A_lds[abase + 2 * 2048 + 1 * 1024]);

        // ---- 12 MFMA, two accumulators alternate ----
        acc0 = __builtin_amdgcn_mfma_f32_32x32x16_bf16(a0h, b0h, acc0, 0, 0, 0);
        acc1 = __builtin_amdgcn_mfma_f32_32x32x16_bf16(a0h, b0m, acc1, 0, 0, 0);
        acc0 = __builtin_amdgcn_mfma_f32_32x32x16_bf16(a0m, b0h, acc0, 0, 0, 0);
        acc1 = __builtin_amdgcn_mfma_f32_32x32x16_bf16(a0m, b0m, acc1, 0, 0, 0);
        acc0 = __builtin_amdgcn_mfma_f32_32x32x16_bf16(a0h, b0l, acc0, 0, 0, 0);
        acc1 = __builtin_amdgcn_mfma_f32_32x32x16_bf16(a0l, b0h, acc1, 0, 0, 0);

        acc0 = __builtin_amdgcn_mfma_f32_32x32x16_bf16(a1h, b1h, acc0, 0, 0, 0);
        acc1 = __builtin_amdgcn_mfma_f32_32x32x16_bf16(a1h, b1m, acc1, 0, 0, 0);
        acc0 = __builtin_amdgcn_mfma_f32_32x32x16_bf16(a1m, b1h, acc0, 0, 0, 0);
        acc1 = __builtin_amdgcn_mfma_f32_32x32x16_bf16(a1m, b1m, acc1, 0, 0, 0);
        acc0 = __builtin_amdgcn_mfma_f32_32x32x16_bf16(a1h, b1l, acc0, 0, 0, 0);
        acc1 = __builtin_amdgcn_mfma_f32_32x32x16_bf16(a1l, b1h, acc1, 0, 0, 0);

        __syncthreads();
    }

    // ---- acc -> hbuf (C layout: col=lane&31, row=(r&3)+8*(r>>2)+4*(lane>>5)) ----
    {
        const f32x16 f0 = acc0 + acc1;
        const int colb = ct * 32 + (lane & 31);
        const int rowb = rt * 32 + 4 * (lane >> 5);
        #pragma unroll
        for (int r = 0; r < 16; ++r) {
            const int row = (r & 3) + 8 * (r >> 2) + rowb;
            hbuf[row][colb] = f0[r];
        }
    }
    __syncthreads();

    // ---- epilogue: h = gate + eps*softplus(noise); partial top-2 (8 threads/row) ----
    const int rloc = tid >> 3;   // 0..63
    const int q    = tid & 7;    // experts q*8 .. q*8+7
    {
        float v1 = -INFINITY, v2 = -INFINITY;
        int   i1 = -1, i2 = -1;
        const float* ep = eps + (size_t)(row0 + rloc) * ENUM + q * 8;
        #pragma unroll
        for (int v = 0; v < 2; ++v) {
            fx4 gv  = *(const fx4*)&hbuf[rloc][q * 8 + v * 4];
            fx4 nv  = *(const fx4*)&hbuf[rloc][ENUM + q * 8 + v * 4];
            fx4 ev  = *(const fx4*)(ep + v * 4);
            fx4 gbv = *(const fx4*)(gb + q * 8 + v * 4);
            fx4 nbv = *(const fx4*)(nb + q * 8 + v * 4);
            #pragma unroll
            for (int j = 0; j < 4; ++j) {
                float nz = nv[j] + nbv[j];
                float sp = fmaxf(nz, 0.f) + log1pf(expf(-fabsf(nz)));
                float h  = gv[j] + gbv[j] + ev[j] * sp;
                int   e  = q * 8 + v * 4 + j;
                if (h > v1)      { v2 = v1; i2 = i1; v1 = h; i1 = e; }
                else if (h > v2) { v2 = h;  i2 = e; }
            }
        }
        pv1[rloc][q] = v1; pv2[rloc][q] = v2;
        pi1[rloc][q] = i1; pi2[rloc][q] = i2;
    }
    __syncthreads();

    if (tid < TM) {
        float v1 = -INFINITY, v2 = -INFINITY;
        int   i1 = -1, i2 = -1;
        #pragma unroll
        for (int qq = 0; qq < 8; ++qq) {
            float a1 = pv1[tid][qq]; int b1 = pi1[tid][qq];
            float a2 = pv2[tid][qq]; int b2 = pi2[tid][qq];
            if (a1 > v1)      { v2 = v1; i2 = i1; v1 = a1; i1 = b1; }
            else if (a1 > v2) { v2 = a1; i2 = b1; }
            if (a2 > v1)      { v2 = v1; i2 = i1; v1 = a2; i1 = b2; }
            else if (a2 > v2) { v2 = a2; i2 = b2; }
        }
        float e2  = expf(v2 - v1);
        float inv = 1.f / (1.f + e2);
        tp1[tid] = inv;
        tp2[tid] = e2 * inv;
        ti1[tid] = i1; ti2[tid] = i2;
    }
    __syncthreads();

    {
        const int   orow = tid >> 3;
        const int   oq   = tid & 7;
        const int   a1 = ti1[orow], a2 = ti2[orow];
        const float p1 = tp1[orow], p2 = tp2[orow];
        float* op = out + (size_t)(row0 + orow) * ENUM + oq * 8;
        #pragma unroll
        for (int v = 0; v < 2; ++v) {
            fx4 o;
            #pragma unroll
            for (int j = 0; j < 4; ++j) {
                int e = oq * 8 + v * 4 + j;
                o[j] = (e == a1) ? p1 : ((e == a2) ? p2 : 0.f);
            }
            *(fx4*)(op + v * 4) = o;
        }
    }
}

extern "C" void kernel_launch(void* const* d_in, const int* in_sizes, int n_in,
                              void* d_out, int out_size, void* d_ws, size_t ws_size,
                              hipStream_t stream) {
    const float* x   = (const float*)d_in[0];
    const float* eps = (const float*)d_in[1];
    const float* Wg  = (const float*)d_in[2];
    const float* gbp = (const float*)d_in[3];
    const float* Wn  = (const float*)d_in[4];
    const float* nbp = (const float*)d_in[5];
    float* out = (float*)d_out;
    unsigned short* wsB = (unsigned short*)d_ws;   // needs 1.5 MB

    hipLaunchKernelGGL(convert_w, dim3(128), dim3(256), 0, stream, Wg, Wn, wsB);

    const int M = in_sizes[0] / DDIM;    // 16384
    hipLaunchKernelGGL(noisy_topk_mfma, dim3(M / TM), dim3(512), 0, stream,
                       x, eps, gbp, nbp, wsB, out);
}

// Round 10
// 76.933 us; speedup vs baseline: 1.7714x; 1.0753x over previous
//
#include <hip/hip_runtime.h>
#include <math.h>

typedef float fx4    __attribute__((ext_vector_type(4)));
typedef float f32x16 __attribute__((ext_vector_type(16)));
typedef short bf16x8 __attribute__((ext_vector_type(8)));
typedef unsigned int ux4 __attribute__((ext_vector_type(4)));

#define TM    64
#define DDIM  2048
#define ENUM  64
#define NKT   128            // k-tiles of 16 over full K

__device__ __forceinline__ unsigned short bf16_rne(float f) {
    unsigned int u = __builtin_bit_cast(unsigned int, f);
    unsigned int r = u + 0x7FFFu + ((u >> 16) & 1u);
    return (unsigned short)(r >> 16);
}
__device__ __forceinline__ float bf16_f32(unsigned short h) {
    unsigned int u = ((unsigned int)h) << 16;
    return __builtin_bit_cast(float, u);
}

// ---------------- kernel 1: W -> bf16x3, frag-slot order (R8-proven, unchanged) ----------------
// wsB 16-B slots: [split(3)][kt(128)][ct(4)][lane(64)]
__global__ __launch_bounds__(256)
void convert_w(const float* __restrict__ Wg, const float* __restrict__ Wn,
               unsigned short* __restrict__ wsB) {
    const int t  = blockIdx.x * 256 + threadIdx.x;   // 0..32767
    const int l  = t & 63;
    const int ct = (t >> 6) & 3;
    const int kt = t >> 8;                            // 0..127
    const int col = ct * 32 + (l & 31);
    const int k0  = kt * 16 + (l >> 5) * 8;
    const float* src = ((col < ENUM) ? (Wg + (size_t)col * DDIM)
                                     : (Wn + (size_t)(col - ENUM) * DDIM)) + k0;
    bf16x8 vh, vm, vl;
    #pragma unroll
    for (int j = 0; j < 8; ++j) {
        float v = src[j];
        unsigned short h = bf16_rne(v);  float r1 = v  - bf16_f32(h);
        unsigned short m = bf16_rne(r1); float r2 = r1 - bf16_f32(m);
        unsigned short o = bf16_rne(r2);
        vh[j] = (short)h; vm[j] = (short)m; vl[j] = (short)o;
    }
    *(bf16x8*)(wsB + ((size_t)(0 * 32768 + t)) * 8) = vh;
    *(bf16x8*)(wsB + ((size_t)(1 * 32768 + t)) * 8) = vm;
    *(bf16x8*)(wsB + ((size_t)(2 * 32768 + t)) * 8) = vl;
}

// in-register bf16x3 split of 8 floats (bit-identical to convert_w's RNE split)
__device__ __forceinline__ void split3x8(fx4 a, fx4 b, bf16x8& H, bf16x8& M, bf16x8& L) {
    unsigned th[8], tm[8], tl[8];
    #pragma unroll
    for (int j = 0; j < 8; ++j) {
        float v = (j < 4) ? a[j] : b[j - 4];
        unsigned u  = __builtin_bit_cast(unsigned, v);
        unsigned t0 = u + 0x7FFFu + ((u >> 16) & 1u);
        float hf = __builtin_bit_cast(float, t0 & 0xFFFF0000u);
        float r1 = v - hf;
        unsigned u1 = __builtin_bit_cast(unsigned, r1);
        unsigned t1 = u1 + 0x7FFFu + ((u1 >> 16) & 1u);
        float mf = __builtin_bit_cast(float, t1 & 0xFFFF0000u);
        float r2 = r1 - mf;
        unsigned u2 = __builtin_bit_cast(unsigned, r2);
        unsigned t2 = u2 + 0x7FFFu + ((u2 >> 16) & 1u);
        th[j] = t0; tm[j] = t1; tl[j] = t2;
    }
    ux4 hw, mw, lw;
    #pragma unroll
    for (int j = 0; j < 4; ++j) {
        hw[j] = __builtin_amdgcn_perm(th[2*j+1], th[2*j], 0x07060302u);
        mw[j] = __builtin_amdgcn_perm(tm[2*j+1], tm[2*j], 0x07060302u);
        lw[j] = __builtin_amdgcn_perm(tl[2*j+1], tl[2*j], 0x07060302u);
    }
    H = __builtin_bit_cast(bf16x8, hw);
    M = __builtin_bit_cast(bf16x8, mw);
    L = __builtin_bit_cast(bf16x8, lw);
}

#define MFMA32 __builtin_amdgcn_mfma_f32_32x32x16_bf16

// ---------------- kernel 2: barrier-free K-loop MFMA GEMM + fused noisy-top2 ----------------
__global__ __launch_bounds__(512, 2)
void noisy_topk_mfma(const float* __restrict__ x,
                     const float* __restrict__ eps,
                     const float* __restrict__ gb,
                     const float* __restrict__ nb,
                     const unsigned short* __restrict__ wsB,
                     float* __restrict__ out)
{
    __shared__ float hbuf[TM][132];     // 33.8 KB
    __shared__ float pv1[TM][8], pv2[TM][8];
    __shared__ int   pi1[TM][8], pi2[TM][8];
    __shared__ float tp1[TM], tp2[TM];
    __shared__ int   ti1[TM], ti2[TM];

    const int tid  = threadIdx.x;
    const int lane = tid & 63;
    const int wv   = tid >> 6;           // 0..7
    const int cth  = wv & 1;             // col half: ct pair {2cth, 2cth+1}
    const int kh   = wv >> 1;            // k quarter 0..3 (512 k each)
    const int bs   = (blockIdx.x & 7) * 32 + (blockIdx.x >> 3);  // XCD swizzle
    const int row0 = bs * TM;

    const int r32 = lane & 31;
    const int k8  = (lane >> 5) * 8;
    const int ct0 = cth * 2;

    // A: direct global, MFMA fragment order (lane -> row r32, k offset k8)
    const float* xa0 = x + (size_t)(row0 + r32) * DDIM + kh * 512 + k8;
    const float* xa1 = xa0 + (size_t)32 * DDIM;

    // B: wsB frag slots; element offset = ((s*128 + kh*32 + kt)*4 + ct)*512 + lane*8
    const unsigned short* bq2 = wsB + (size_t)kh * 65536 + ct0 * 512 + lane * 8;
    // per s: +262144 ; per kt: +2048 ; ct1 = ct0+1: +512

    f32x16 aA = {}, aB = {}, aC = {}, aD = {};

    #define LDA(ra, rb, sa, sb, kt) do { \
        ra = *(const fx4*)(xa0 + (kt) * 16); \
        rb = *(const fx4*)(xa0 + (kt) * 16 + 4); \
        sa = *(const fx4*)(xa1 + (kt) * 16); \
        sb = *(const fx4*)(xa1 + (kt) * 16 + 4); \
    } while (0)

    #define KTILE(ra, rb, sa, sb, kt) do { \
        const int _ko = (kt) * 2048; \
        bf16x8 Bh0 = *(const bf16x8*)(bq2 + _ko); \
        bf16x8 Bm0 = *(const bf16x8*)(bq2 + _ko + 262144); \
        bf16x8 Bl0 = *(const bf16x8*)(bq2 + _ko + 524288); \
        bf16x8 Bh1 = *(const bf16x8*)(bq2 + _ko + 512); \
        bf16x8 Bm1 = *(const bf16x8*)(bq2 + _ko + 262144 + 512); \
        bf16x8 Bl1 = *(const bf16x8*)(bq2 + _ko + 524288 + 512); \
        bf16x8 A0h, A0m, A0l, A1h, A1m, A1l; \
        split3x8(ra, rb, A0h, A0m, A0l); \
        split3x8(sa, sb, A1h, A1m, A1l); \
        aA = MFMA32(A0h, Bh0, aA, 0, 0, 0); aB = MFMA32(A0h, Bh1, aB, 0, 0, 0); \
        aC = MFMA32(A1h, Bh0, aC, 0, 0, 0); aD = MFMA32(A1h, Bh1, aD, 0, 0, 0); \
        aA = MFMA32(A0h, Bm0, aA, 0, 0, 0); aB = MFMA32(A0h, Bm1, aB, 0, 0, 0); \
        aC = MFMA32(A1h, Bm0, aC, 0, 0, 0); aD = MFMA32(A1h, Bm1, aD, 0, 0, 0); \
        aA = MFMA32(A0m, Bh0, aA, 0, 0, 0); aB = MFMA32(A0m, Bh1, aB, 0, 0, 0); \
        aC = MFMA32(A1m, Bh0, aC, 0, 0, 0); aD = MFMA32(A1m, Bh1, aD, 0, 0, 0); \
        aA = MFMA32(A0m, Bm0, aA, 0, 0, 0); aB = MFMA32(A0m, Bm1, aB, 0, 0, 0); \
        aC = MFMA32(A1m, Bm0, aC, 0, 0, 0); aD = MFMA32(A1m, Bm1, aD, 0, 0, 0); \
        aA = MFMA32(A0h, Bl0, aA, 0, 0, 0); aB = MFMA32(A0h, Bl1, aB, 0, 0, 0); \
        aC = MFMA32(A1h, Bl0, aC, 0, 0, 0); aD = MFMA32(A1h, Bl1, aD, 0, 0, 0); \
        aA = MFMA32(A0l, Bh0, aA, 0, 0, 0); aB = MFMA32(A0l, Bh1, aB, 0, 0, 0); \
        aC = MFMA32(A1l, Bh0, aC, 0, 0, 0); aD = MFMA32(A1l, Bh1, aD, 0, 0, 0); \
    } while (0)

    // ---- barrier-free K loop: 32 ktiles, P/Q ping-pong, A prefetched 1 ktile ahead ----
    fx4 p0, p1, p2, p3, q0, q1, q2, q3;
    LDA(p0, p1, p2, p3, 0);
    LDA(q0, q1, q2, q3, 1);
    for (int kt = 0; kt + 2 < 32; kt += 2) {
        KTILE(p0, p1, p2, p3, kt);
        LDA(p0, p1, p2, p3, kt + 2);
        KTILE(q0, q1, q2, q3, kt + 1);
        LDA(q0, q1, q2, q3, kt + 3);
    }
    KTILE(p0, p1, p2, p3, 30);
    KTILE(q0, q1, q2, q3, 31);

    #undef KTILE
    #undef LDA

    // ---- combine K-quarters in hbuf (C layout: col=lane&31, row=(r&3)+8*(r>>2)+4*(lane>>5)) ----
    const int colA = ct0 * 32 + r32;
    const int colB = colA + 32;
    const int rb4  = 4 * (lane >> 5);
    if (kh == 0) {
        #pragma unroll
        for (int r = 0; r < 16; ++r) {
            const int row = (r & 3) + 8 * (r >> 2) + rb4;
            hbuf[row][colA]      = aA[r];
            hbuf[row][colB]      = aB[r];
            hbuf[row + 32][colA] = aC[r];
            hbuf[row + 32][colB] = aD[r];
        }
    }
    __syncthreads();
    if (kh == 1) {
        #pragma unroll
        for (int r = 0; r < 16; ++r) {
            const int row = (r & 3) + 8 * (r >> 2) + rb4;
            hbuf[row][colA]      += aA[r];
            hbuf[row][colB]      += aB[r];
            hbuf[row + 32][colA] += aC[r];
            hbuf[row + 32][colB] += aD[r];
        }
    }
    __syncthreads();
    if (kh == 2) {
        #pragma unroll
        for (int r = 0; r < 16; ++r) {
            const int row = (r & 3) + 8 * (r >> 2) + rb4;
            hbuf[row][colA]      += aA[r];
            hbuf[row][colB]      += aB[r];
            hbuf[row + 32][colA] += aC[r];
            hbuf[row + 32][colB] += aD[r];
        }
    }
    __syncthreads();
    if (kh == 3) {
        #pragma unroll
        for (int r = 0; r < 16; ++r) {
            const int row = (r & 3) + 8 * (r >> 2) + rb4;
            hbuf[row][colA]      += aA[r];
            hbuf[row][colB]      += aB[r];
            hbuf[row + 32][colA] += aC[r];
            hbuf[row + 32][colB] += aD[r];
        }
    }
    __syncthreads();

    // ---- epilogue (R9-proven): h = gate + eps*softplus(noise); top-2; softmax; store ----
    const int rloc = tid >> 3;   // 0..63
    const int q    = tid & 7;    // experts q*8 .. q*8+7
    {
        float v1 = -INFINITY, v2 = -INFINITY;
        int   i1 = -1, i2 = -1;
        const float* ep = eps + (size_t)(row0 + rloc) * ENUM + q * 8;
        #pragma unroll
        for (int v = 0; v < 2; ++v) {
            fx4 gv  = *(const fx4*)&hbuf[rloc][q * 8 + v * 4];
            fx4 nv  = *(const fx4*)&hbuf[rloc][ENUM + q * 8 + v * 4];
            fx4 ev  = *(const fx4*)(ep + v * 4);
            fx4 gbv = *(const fx4*)(gb + q * 8 + v * 4);
            fx4 nbv = *(const fx4*)(nb + q * 8 + v * 4);
            #pragma unroll
            for (int j = 0; j < 4; ++j) {
                float nz = nv[j] + nbv[j];
                float sp = fmaxf(nz, 0.f) + log1pf(expf(-fabsf(nz)));
                float h  = gv[j] + gbv[j] + ev[j] * sp;
                int   e  = q * 8 + v * 4 + j;
                if (h > v1)      { v2 = v1; i2 = i1; v1 = h; i1 = e; }
                else if (h > v2) { v2 = h;  i2 = e; }
            }
        }
        pv1[rloc][q] = v1; pv2[rloc][q] = v2;
        pi1[rloc][q] = i1; pi2[rloc][q] = i2;
    }
    __syncthreads();

    if (tid < TM) {
        float v1 = -INFINITY, v2 = -INFINITY;
        int   i1 = -1, i2 = -1;
        #pragma unroll
        for (int qq = 0; qq < 8; ++qq) {
            float a1 = pv1[tid][qq]; int b1 = pi1[tid][qq];
            float a2 = pv2[tid][qq]; int b2 = pi2[tid][qq];
            if (a1 > v1)      { v2 = v1; i2 = i1; v1 = a1; i1 = b1; }
            else if (a1 > v2) { v2 = a1; i2 = b1; }
            if (a2 > v1)      { v2 = v1; i2 = i1; v1 = a2; i1 = b2; }
            else if (a2 > v2) { v2 = a2; i2 = b2; }
        }
        float e2  = expf(v2 - v1);
        float inv = 1.f / (1.f + e2);
        tp1[tid] = inv;
        tp2[tid] = e2 * inv;
        ti1[tid] = i1; ti2[tid] = i2;
    }
    __syncthreads();

    {
        const int   orow = tid >> 3;
        const int   oq   = tid & 7;
        const int   a1 = ti1[orow], a2 = ti2[orow];
        const float p1 = tp1[orow], p2 = tp2[orow];
        float* op = out + (size_t)(row0 + orow) * ENUM + oq * 8;
        #pragma unroll
        for (int v = 0; v < 2; ++v) {
            fx4 o;
            #pragma unroll
            for (int j = 0; j < 4; ++j) {
                int e = oq * 8 + v * 4 + j;
                o[j] = (e == a1) ? p1 : ((e == a2) ? p2 : 0.f);
            }
            *(fx4*)(op + v * 4) = o;
        }
    }
}

extern "C" void kernel_launch(void* const* d_in, const int* in_sizes, int n_in,
                              void* d_out, int out_size, void* d_ws, size_t ws_size,
                              hipStream_t stream) {
    const float* x   = (const float*)d_in[0];
    const float* eps = (const float*)d_in[1];
    const float* Wg  = (const float*)d_in[2];
    const float* gbp = (const float*)d_in[3];
    const float* Wn  = (const float*)d_in[4];
    const float* nbp = (const float*)d_in[5];
    float* out = (float*)d_out;
    unsigned short* wsB = (unsigned short*)d_ws;   // needs 1.5 MB

    hipLaunchKernelGGL(convert_w, dim3(128), dim3(256), 0, stream, Wg, Wn, wsB);

    const int M = in_sizes[0] / DDIM;    // 16384
    hipLaunchKernelGGL(noisy_topk_mfma, dim3(M / TM), dim3(512), 0, stream,
                       x, eps, gbp, nbp, wsB, out);
}